// Round 1
// baseline (389.515 us; speedup 1.0000x reference)
//
#include <hip/hip_runtime.h>
#include <hip/hip_bf16.h>

#define NN   8192
#define DIN  512
#define DOUT 256

typedef __attribute__((ext_vector_type(8))) short s16x8;   // 8 bf16 (A/B frag)
typedef __attribute__((ext_vector_type(4))) float f32x4;   // C/D frag

static __device__ __forceinline__ unsigned short f2bf(float f) {
    union { float f; unsigned u; } v; v.f = f;
    unsigned r = v.u + 0x7fffu + ((v.u >> 16) & 1u);   // RNE
    return (unsigned short)(r >> 16);
}

// ---------------- Kernel 1: Wh = features @ W (fp32), plus WhT in bf16 ----------------
// block = 256 threads, 16 rows x 256 cols per block. grid = 512.
__global__ __launch_bounds__(256) void k_wh(const float* __restrict__ feat,
                                            const float* __restrict__ W,
                                            float* __restrict__ Wh,
                                            unsigned short* __restrict__ WhT) {
    __shared__ float lf[16 * DIN];                 // 32 KB
    const int tid = threadIdx.x;
    const int i0  = blockIdx.x * 16;

    const float4* fsrc = (const float4*)(feat + (size_t)i0 * DIN);
    float4* fdst = (float4*)lf;
    #pragma unroll
    for (int q = 0; q < 8; ++q) fdst[tid + q * 256] = fsrc[tid + q * 256];
    __syncthreads();

    const int c = tid;                              // output channel
    float outs[16];
    #pragma unroll
    for (int r = 0; r < 16; ++r) outs[r] = 0.f;

    for (int k = 0; k < DIN; k += 4) {
        float w0 = W[(k + 0) * DOUT + c];
        float w1 = W[(k + 1) * DOUT + c];
        float w2 = W[(k + 2) * DOUT + c];
        float w3 = W[(k + 3) * DOUT + c];
        #pragma unroll
        for (int r = 0; r < 16; ++r) {
            float4 f = *(const float4*)&lf[r * DIN + k];   // broadcast read
            outs[r] = fmaf(f.x, w0, fmaf(f.y, w1, fmaf(f.z, w2, fmaf(f.w, w3, outs[r]))));
        }
    }

    unsigned short tb[16];
    #pragma unroll
    for (int r = 0; r < 16; ++r) {
        Wh[(size_t)(i0 + r) * DOUT + c] = outs[r];
        tb[r] = f2bf(outs[r]);
    }
    // WhT[c][i0 .. i0+16): 32 contiguous bytes per thread
    uint4* wt = (uint4*)(WhT + (size_t)c * NN + i0);
    wt[0] = *(uint4*)&tb[0];
    wt[1] = *(uint4*)&tb[8];
}

// ---------------- Kernel 1b: src/dst = Wh @ a halves. 4 rows/block (1 per wave) ------
__global__ __launch_bounds__(256) void k_srcdst(const float* __restrict__ Wh,
                                                const float* __restrict__ a,
                                                float* __restrict__ src,
                                                float* __restrict__ dst) {
    const int w = threadIdx.x >> 6, lane = threadIdx.x & 63;
    const int i = blockIdx.x * 4 + w;
    const float* row = Wh + (size_t)i * DOUT;
    float sv = 0.f, dv = 0.f;
    #pragma unroll
    for (int q = 0; q < 4; ++q) {
        int cc = lane + q * 64;
        float v = row[cc];
        sv = fmaf(v, a[cc], sv);
        dv = fmaf(v, a[DOUT + cc], dv);
    }
    #pragma unroll
    for (int off = 32; off; off >>= 1) {
        sv += __shfl_xor(sv, off);
        dv += __shfl_xor(dv, off);
    }
    if (lane == 0) { src[i] = sv; dst[i] = dv; }
}

// ---------------- Kernel 2: per-row max, 1/denominator, and adj bitmask --------------
// one block (256 th) per row; wave w covers j in [w*2048, w*2048+2048)
__global__ __launch_bounds__(256) void k_rowstats(const int* __restrict__ adj,
                                                  const float* __restrict__ src,
                                                  const float* __restrict__ dst,
                                                  float* __restrict__ mrow,
                                                  float* __restrict__ rinv,
                                                  unsigned int* __restrict__ bits) {
    const int i = blockIdx.x;
    const int w = threadIdx.x >> 6, lane = threadIdx.x & 63;
    const float si = src[i];
    const int* arow = adj + (size_t)i * NN;

    float evals[32];
    unsigned int lm = 0;
    float lmax = -1e30f;
    const int jb0 = w * 2048;

    #pragma unroll
    for (int it = 0; it < 32; ++it) {
        int j = jb0 + it * 64 + lane;
        int av = arow[j];
        float x = si + dst[j];
        x = fmaxf(x, 0.2f * x);                    // leaky_relu(x, 0.2)
        evals[it] = x;
        bool act = av > 0;
        unsigned long long bal = __ballot(act);
        if (act) { lm |= (1u << it); lmax = fmaxf(lmax, x); }
        if (lane == 0) {
            int wi = (jb0 + it * 64) >> 5;
            bits[(size_t)i * 256 + wi]     = (unsigned int)bal;
            bits[(size_t)i * 256 + wi + 1] = (unsigned int)(bal >> 32);
        }
    }
    #pragma unroll
    for (int off = 32; off; off >>= 1) lmax = fmaxf(lmax, __shfl_xor(lmax, off));

    __shared__ float red[8];
    if (lane == 0) red[w] = lmax;
    __syncthreads();
    const float m = fmaxf(fmaxf(red[0], red[1]), fmaxf(red[2], red[3]));

    float s = 0.f;
    #pragma unroll
    for (int it = 0; it < 32; ++it)
        if ((lm >> it) & 1u) s += __expf(evals[it] - m);
    #pragma unroll
    for (int off = 32; off; off >>= 1) s += __shfl_xor(s, off);
    if (lane == 0) red[4 + w] = s;
    __syncthreads();
    if (threadIdx.x == 0) {
        float tot = red[4] + red[5] + red[6] + red[7];
        mrow[i] = m;
        rinv[i] = tot > 0.f ? 1.f / tot : 0.f;
    }
}

// ---------------- Kernel 3: h = softmax(P) @ Wh via MFMA, fused ELU ------------------
// grid = 128 row-tiles x 4 channel-quads = 512 blocks. block = 256 th = 4 waves.
// wave: 16 rows x 64 channels (4 MFMA n-tiles), K-loop over j in steps of 32.
#define LBS 40   // padded LDS stride (bf16 elems) per channel row
__global__ __launch_bounds__(256) void k_attn(const unsigned short* __restrict__ WhT,
                                              const float* __restrict__ src,
                                              const float* __restrict__ dst,
                                              const float* __restrict__ mrow,
                                              const float* __restrict__ rinv,
                                              const unsigned int* __restrict__ bits,
                                              float* __restrict__ out) {
    __shared__ unsigned short lb[64 * LBS];        // 5 KB: WhT slab [64 ch][32 k]
    const int tid  = threadIdx.x;
    const int w    = tid >> 6, lane = tid & 63;
    const int rt   = blockIdx.x >> 2;
    const int C0   = (blockIdx.x & 3) * 64;
    const int i0   = rt * 64 + w * 16;
    const int cl   = lane & 15, lk = lane >> 4;
    const int koff = lk * 8;

    const int   ia = i0 + cl;                      // A-frag row for this lane
    const float si = src[ia];
    const float mi = mrow[ia];
    const unsigned int* brow = bits + (size_t)ia * 256;

    // staging map: one 16B chunk per thread per step
    const int scc = tid >> 2, sqt = tid & 3;

    f32x4 acc[4];
    #pragma unroll
    for (int t = 0; t < 4; ++t) { acc[t][0]=0.f; acc[t][1]=0.f; acc[t][2]=0.f; acc[t][3]=0.f; }

    for (int kk = 0; kk < 256; ++kk) {
        const int k0 = kk * 32;
        __syncthreads();
        {   // stage WhT[C0..C0+64)[k0..k0+32) -> lb
            uint4 v = *(const uint4*)(WhT + (size_t)(C0 + scc) * NN + k0 + sqt * 8);
            *(uint4*)&lb[scc * LBS + sqt * 8] = v;
        }
        __syncthreads();

        // build A fragment: P[ia][k0+koff .. +8]
        const unsigned int mw = brow[kk];
        float4 d0 = *(const float4*)(dst + k0 + koff);
        float4 d1 = *(const float4*)(dst + k0 + koff + 4);
        float dd[8] = {d0.x, d0.y, d0.z, d0.w, d1.x, d1.y, d1.z, d1.w};
        s16x8 af;
        #pragma unroll
        for (int jj = 0; jj < 8; ++jj) {
            float x = si + dd[jj];
            x = fmaxf(x, 0.2f * x);
            float p = ((mw >> (koff + jj)) & 1u) ? __expf(x - mi) : 0.f;
            af[jj] = (short)f2bf(p);
        }
        #pragma unroll
        for (int t = 0; t < 4; ++t) {
            s16x8 bf = *(const s16x8*)&lb[(t * 16 + cl) * LBS + koff];
            acc[t] = __builtin_amdgcn_mfma_f32_16x16x32_bf16(af, bf, acc[t], 0, 0, 0);
        }
    }

    // epilogue: D row = i0 + lk*4 + q, col = C0 + t*16 + cl  (m89-verified C/D layout)
    float rv[4];
    #pragma unroll
    for (int q = 0; q < 4; ++q) rv[q] = rinv[i0 + lk * 4 + q];
    #pragma unroll
    for (int t = 0; t < 4; ++t) {
        int c = C0 + t * 16 + cl;
        #pragma unroll
        for (int q = 0; q < 4; ++q) {
            int io = i0 + lk * 4 + q;
            float v = acc[t][q] * rv[q];
            v = v > 0.f ? v : expm1f(v);           // ELU(alpha=1)
            out[(size_t)io * DOUT + c] = v;
        }
    }
}

extern "C" void kernel_launch(void* const* d_in, const int* in_sizes, int n_in,
                              void* d_out, int out_size, void* d_ws, size_t ws_size,
                              hipStream_t stream) {
    const float* feat = (const float*)d_in[0];
    const int*   adj  = (const int*)d_in[1];
    const float* W    = (const float*)d_in[2];
    const float* a    = (const float*)d_in[3];
    float* out = (float*)d_out;

    char* ws = (char*)d_ws;
    float*          Wh   = (float*)ws;                            // 8 MB
    unsigned short* WhT  = (unsigned short*)(ws + 8388608);       // 4 MB
    float*          src  = (float*)(ws + 12582912);               // 32 KB
    float*          dst  = (float*)(ws + 12615680);               // 32 KB
    float*          mrow = (float*)(ws + 12648448);               // 32 KB
    float*          rinv = (float*)(ws + 12681216);               // 32 KB
    unsigned int*   bits = (unsigned int*)(ws + 12713984);        // 8 MB

    k_wh      <<<512,  256, 0, stream>>>(feat, W, Wh, WhT);
    k_srcdst  <<<2048, 256, 0, stream>>>(Wh, a, src, dst);
    k_rowstats<<<8192, 256, 0, stream>>>(adj, src, dst, mrow, rinv, bits);
    k_attn    <<<512,  256, 0, stream>>>(WhT, src, dst, mrow, rinv, bits, out);
}

// Round 2
// 246.756 us; speedup vs baseline: 1.5785x; 1.5785x over previous
//
#include <hip/hip_runtime.h>
#include <hip/hip_bf16.h>

#define NN   8192
#define DIN  512
#define DOUT 256

typedef __attribute__((ext_vector_type(8))) short s16x8;   // 8 bf16 (A/B frag)
typedef __attribute__((ext_vector_type(4))) float f32x4;   // C/D frag

static __device__ __forceinline__ unsigned short f2bf(float f) {
    union { float f; unsigned u; } v; v.f = f;
    unsigned r = v.u + 0x7fffu + ((v.u >> 16) & 1u);   // RNE
    return (unsigned short)(r >> 16);
}

static __device__ __forceinline__ void gload_lds16(const void* g, void* l) {
    __builtin_amdgcn_global_load_lds(
        (const __attribute__((address_space(1))) unsigned int*)g,
        (__attribute__((address_space(3))) unsigned int*)l, 16, 0, 0);
}

// ---------------- Kernel 1: Wh = features @ W (fp32), plus WhT in bf16 ----------------
__global__ __launch_bounds__(256) void k_wh(const float* __restrict__ feat,
                                            const float* __restrict__ W,
                                            float* __restrict__ Wh,
                                            unsigned short* __restrict__ WhT) {
    __shared__ float lf[16 * DIN];                 // 32 KB
    const int tid = threadIdx.x;
    const int i0  = blockIdx.x * 16;

    const float4* fsrc = (const float4*)(feat + (size_t)i0 * DIN);
    float4* fdst = (float4*)lf;
    #pragma unroll
    for (int q = 0; q < 8; ++q) fdst[tid + q * 256] = fsrc[tid + q * 256];
    __syncthreads();

    const int c = tid;
    float outs[16];
    #pragma unroll
    for (int r = 0; r < 16; ++r) outs[r] = 0.f;

    for (int k = 0; k < DIN; k += 4) {
        float w0 = W[(k + 0) * DOUT + c];
        float w1 = W[(k + 1) * DOUT + c];
        float w2 = W[(k + 2) * DOUT + c];
        float w3 = W[(k + 3) * DOUT + c];
        #pragma unroll
        for (int r = 0; r < 16; ++r) {
            float4 f = *(const float4*)&lf[r * DIN + k];
            outs[r] = fmaf(f.x, w0, fmaf(f.y, w1, fmaf(f.z, w2, fmaf(f.w, w3, outs[r]))));
        }
    }

    unsigned short tb[16];
    #pragma unroll
    for (int r = 0; r < 16; ++r) {
        Wh[(size_t)(i0 + r) * DOUT + c] = outs[r];
        tb[r] = f2bf(outs[r]);
    }
    uint4* wt = (uint4*)(WhT + (size_t)c * NN + i0);
    wt[0] = *(uint4*)&tb[0];
    wt[1] = *(uint4*)&tb[8];
}

// ---------------- Kernel 1b: src/dst = Wh @ a halves ---------------------------------
__global__ __launch_bounds__(256) void k_srcdst(const float* __restrict__ Wh,
                                                const float* __restrict__ a,
                                                float* __restrict__ src,
                                                float* __restrict__ dst) {
    const int w = threadIdx.x >> 6, lane = threadIdx.x & 63;
    const int i = blockIdx.x * 4 + w;
    const float* row = Wh + (size_t)i * DOUT;
    float sv = 0.f, dv = 0.f;
    #pragma unroll
    for (int q = 0; q < 4; ++q) {
        int cc = lane + q * 64;
        float v = row[cc];
        sv = fmaf(v, a[cc], sv);
        dv = fmaf(v, a[DOUT + cc], dv);
    }
    #pragma unroll
    for (int off = 32; off; off >>= 1) {
        sv += __shfl_xor(sv, off);
        dv += __shfl_xor(dv, off);
    }
    if (lane == 0) { src[i] = sv; dst[i] = dv; }
}

// ============================ PLAN A (large workspace) ================================
// Kernel 2a: per-row softmax stats AND normalized bf16 P write (mask + rinv folded in).
__global__ __launch_bounds__(256) void k_rowstats_a(const int* __restrict__ adj,
                                                    const float* __restrict__ src,
                                                    const float* __restrict__ dst,
                                                    unsigned short* __restrict__ P) {
    const int i = blockIdx.x;
    const int w = threadIdx.x >> 6, lane = threadIdx.x & 63;
    const float si = src[i];
    const int jb = w * 2048;

    float ev[32];
    unsigned int actm = 0;
    float lmax = -1e30f;
    #pragma unroll
    for (int it = 0; it < 16; ++it) {
        int j = jb + it * 128 + lane * 2;
        int2 av = *(const int2*)(adj + (size_t)i * NN + j);
        float2 dv = *(const float2*)(dst + j);
        float x0 = si + dv.x; x0 = fmaxf(x0, 0.2f * x0);
        float x1 = si + dv.y; x1 = fmaxf(x1, 0.2f * x1);
        ev[2 * it]     = x0;
        ev[2 * it + 1] = x1;
        if (av.x > 0) { actm |= 1u << (2 * it);     lmax = fmaxf(lmax, x0); }
        if (av.y > 0) { actm |= 1u << (2 * it + 1); lmax = fmaxf(lmax, x1); }
    }
    #pragma unroll
    for (int off = 32; off; off >>= 1) lmax = fmaxf(lmax, __shfl_xor(lmax, off));

    __shared__ float red[8];
    if (lane == 0) red[w] = lmax;
    __syncthreads();
    const float m = fmaxf(fmaxf(red[0], red[1]), fmaxf(red[2], red[3]));

    float s = 0.f;
    #pragma unroll
    for (int t = 0; t < 32; ++t) {
        float p = ((actm >> t) & 1u) ? __expf(ev[t] - m) : 0.f;
        ev[t] = p;
        s += p;
    }
    #pragma unroll
    for (int off = 32; off; off >>= 1) s += __shfl_xor(s, off);
    if (lane == 0) red[4 + w] = s;
    __syncthreads();
    const float tot = red[4] + red[5] + red[6] + red[7];
    const float rinv = tot > 0.f ? 1.f / tot : 0.f;

    #pragma unroll
    for (int it = 0; it < 16; ++it) {
        unsigned short b0 = f2bf(ev[2 * it]     * rinv);
        unsigned short b1 = f2bf(ev[2 * it + 1] * rinv);
        unsigned int pk = (unsigned)b0 | ((unsigned)b1 << 16);
        *(unsigned int*)(P + (size_t)i * NN + jb + it * 128 + lane * 2) = pk;
    }
}

// Kernel 3a: part[ks] = P[rows, kchunk] @ WhT[:, kchunk]^T  — m97-style bf16 GEMM.
// BM=128, BN=256(=DOUT), BK=64, KSPLIT=4 (chunk 2048). 512 threads = 8 waves (2x4).
__global__ __launch_bounds__(512) void k_pgemm(const unsigned short* __restrict__ P,
                                               const unsigned short* __restrict__ WhT,
                                               float* __restrict__ part) {
    __shared__ unsigned short As[128 * 64];   // 16 KB, [row][k] bf16, swizzled storage
    __shared__ unsigned short Bs[256 * 64];   // 32 KB

    const int tid  = threadIdx.x;
    const int w    = tid >> 6, lane = tid & 63;
    const int cl   = lane & 15, lk = lane >> 4;
    const int rt   = blockIdx.x & 63;
    const int ks   = blockIdx.x >> 6;                 // 0..3
    const int i0   = rt * 128;
    const int kb0  = ks * 2048;
    const int wr   = w >> 2, wc = w & 3;              // wave tile: 64 rows x 64 cols

    f32x4 acc[4][4];
    #pragma unroll
    for (int m = 0; m < 4; ++m)
        #pragma unroll
        for (int n = 0; n < 4; ++n) { acc[m][n][0]=0.f; acc[m][n][1]=0.f; acc[m][n][2]=0.f; acc[m][n][3]=0.f; }

    // staging source maps (pre-swizzled global source, linear LDS dest — m173 pattern)
    // chunk -> row = chunk>>3, kb = (chunk&7)*16 bytes, swz kb ^= ((row&7)<<4)
    int rowA[2], kbA[2];
    #pragma unroll
    for (int q = 0; q < 2; ++q) {
        int chunk = q * 512 + tid;
        rowA[q] = chunk >> 3;
        kbA[q]  = ((chunk & 7) * 16) ^ ((rowA[q] & 7) << 4);
    }
    int rowB[4], kbB[4];
    #pragma unroll
    for (int q = 0; q < 4; ++q) {
        int chunk = q * 512 + tid;
        rowB[q] = chunk >> 3;
        kbB[q]  = ((chunk & 7) * 16) ^ ((rowB[q] & 7) << 4);
    }

    const char* Abase = (const char*)(P   + (size_t)i0 * NN + kb0);
    const char* Bbase = (const char*)(WhT +                   kb0);

    for (int kt = 0; kt < 32; ++kt) {
        const size_t kbyte = (size_t)kt * 128;        // 64 bf16 per step
        __syncthreads();
        #pragma unroll
        for (int q = 0; q < 2; ++q)
            gload_lds16(Abase + (size_t)rowA[q] * (NN * 2) + kbyte + kbA[q],
                        (char*)As + (q * 512 + w * 64) * 16);
        #pragma unroll
        for (int q = 0; q < 4; ++q)
            gload_lds16(Bbase + (size_t)rowB[q] * (NN * 2) + kbyte + kbB[q],
                        (char*)Bs + (q * 512 + w * 64) * 16);
        __syncthreads();   // implies vmcnt(0) drain

        #pragma unroll
        for (int h = 0; h < 2; ++h) {
            s16x8 af[4], bf[4];
            const int kw = h * 64 + lk * 16;          // byte offset along k
            #pragma unroll
            for (int m = 0; m < 4; ++m) {
                int row  = wr * 64 + m * 16 + cl;
                af[m] = *(const s16x8*)((const char*)As + row * 128 + (kw ^ ((row & 7) << 4)));
                int rowb = wc * 64 + m * 16 + cl;
                bf[m] = *(const s16x8*)((const char*)Bs + rowb * 128 + (kw ^ ((rowb & 7) << 4)));
            }
            #pragma unroll
            for (int m = 0; m < 4; ++m)
                #pragma unroll
                for (int n = 0; n < 4; ++n)
                    acc[m][n] = __builtin_amdgcn_mfma_f32_16x16x32_bf16(af[m], bf[n], acc[m][n], 0, 0, 0);
        }
    }

    float* pp = part + (size_t)ks * (NN * DOUT);
    #pragma unroll
    for (int m = 0; m < 4; ++m) {
        #pragma unroll
        for (int n = 0; n < 4; ++n) {
            int colg = wc * 64 + n * 16 + cl;
            #pragma unroll
            for (int q = 0; q < 4; ++q) {
                int rowg = i0 + wr * 64 + m * 16 + lk * 4 + q;
                pp[(size_t)rowg * DOUT + colg] = acc[m][n][q];
            }
        }
    }
}

// Kernel 4a: out = elu(sum of 4 partials)
__global__ __launch_bounds__(256) void k_finish(const float* __restrict__ part,
                                                float* __restrict__ out) {
    const int idx = blockIdx.x * 256 + threadIdx.x;   // f32x4 units
    const int stride = NN * DOUT / 4;
    float4 a = ((const float4*)part)[idx];
    float4 b = ((const float4*)part)[idx + stride];
    float4 c = ((const float4*)part)[idx + 2 * stride];
    float4 d = ((const float4*)part)[idx + 3 * stride];
    float4 s;
    s.x = a.x + b.x + c.x + d.x;
    s.y = a.y + b.y + c.y + d.y;
    s.z = a.z + b.z + c.z + d.z;
    s.w = a.w + b.w + c.w + d.w;
    s.x = s.x > 0.f ? s.x : expm1f(s.x);
    s.y = s.y > 0.f ? s.y : expm1f(s.y);
    s.z = s.z > 0.f ? s.z : expm1f(s.z);
    s.w = s.w > 0.f ? s.w : expm1f(s.w);
    ((float4*)out)[idx] = s;
}

// ============================ FALLBACK (round-1 path) ================================
__global__ __launch_bounds__(256) void k_rowstats_fb(const int* __restrict__ adj,
                                                     const float* __restrict__ src,
                                                     const float* __restrict__ dst,
                                                     float* __restrict__ mrow,
                                                     float* __restrict__ rinv,
                                                     unsigned int* __restrict__ bits) {
    const int i = blockIdx.x;
    const int w = threadIdx.x >> 6, lane = threadIdx.x & 63;
    const float si = src[i];
    const int* arow = adj + (size_t)i * NN;

    float evals[32];
    unsigned int lm = 0;
    float lmax = -1e30f;
    const int jb0 = w * 2048;

    #pragma unroll
    for (int it = 0; it < 32; ++it) {
        int j = jb0 + it * 64 + lane;
        int av = arow[j];
        float x = si + dst[j];
        x = fmaxf(x, 0.2f * x);
        evals[it] = x;
        bool act = av > 0;
        unsigned long long bal = __ballot(act);
        if (act) { lm |= (1u << it); lmax = fmaxf(lmax, x); }
        if (lane == 0) {
            int wi = (jb0 + it * 64) >> 5;
            bits[(size_t)i * 256 + wi]     = (unsigned int)bal;
            bits[(size_t)i * 256 + wi + 1] = (unsigned int)(bal >> 32);
        }
    }
    #pragma unroll
    for (int off = 32; off; off >>= 1) lmax = fmaxf(lmax, __shfl_xor(lmax, off));

    __shared__ float red[8];
    if (lane == 0) red[w] = lmax;
    __syncthreads();
    const float m = fmaxf(fmaxf(red[0], red[1]), fmaxf(red[2], red[3]));

    float s = 0.f;
    #pragma unroll
    for (int it = 0; it < 32; ++it)
        if ((lm >> it) & 1u) s += __expf(evals[it] - m);
    #pragma unroll
    for (int off = 32; off; off >>= 1) s += __shfl_xor(s, off);
    if (lane == 0) red[4 + w] = s;
    __syncthreads();
    if (threadIdx.x == 0) {
        float tot = red[4] + red[5] + red[6] + red[7];
        mrow[i] = m;
        rinv[i] = tot > 0.f ? 1.f / tot : 0.f;
    }
}

#define LBS 40
__global__ __launch_bounds__(256) void k_attn_fb(const unsigned short* __restrict__ WhT,
                                                 const float* __restrict__ src,
                                                 const float* __restrict__ dst,
                                                 const float* __restrict__ mrow,
                                                 const float* __restrict__ rinv,
                                                 const unsigned int* __restrict__ bits,
                                                 float* __restrict__ out) {
    __shared__ unsigned short lb[64 * LBS];
    const int tid  = threadIdx.x;
    const int w    = tid >> 6, lane = tid & 63;
    const int rt   = blockIdx.x >> 2;
    const int C0   = (blockIdx.x & 3) * 64;
    const int i0   = rt * 64 + w * 16;
    const int cl   = lane & 15, lk = lane >> 4;
    const int koff = lk * 8;

    const int   ia = i0 + cl;
    const float si = src[ia];
    const float mi = mrow[ia];
    const unsigned int* brow = bits + (size_t)ia * 256;
    const int scc = tid >> 2, sqt = tid & 3;

    f32x4 acc[4];
    #pragma unroll
    for (int t = 0; t < 4; ++t) { acc[t][0]=0.f; acc[t][1]=0.f; acc[t][2]=0.f; acc[t][3]=0.f; }

    for (int kk = 0; kk < 256; ++kk) {
        const int k0 = kk * 32;
        __syncthreads();
        {
            uint4 v = *(const uint4*)(WhT + (size_t)(C0 + scc) * NN + k0 + sqt * 8);
            *(uint4*)&lb[scc * LBS + sqt * 8] = v;
        }
        __syncthreads();

        const unsigned int mw = brow[kk];
        float4 d0 = *(const float4*)(dst + k0 + koff);
        float4 d1 = *(const float4*)(dst + k0 + koff + 4);
        float dd[8] = {d0.x, d0.y, d0.z, d0.w, d1.x, d1.y, d1.z, d1.w};
        s16x8 af;
        #pragma unroll
        for (int jj = 0; jj < 8; ++jj) {
            float x = si + dd[jj];
            x = fmaxf(x, 0.2f * x);
            float p = ((mw >> (koff + jj)) & 1u) ? __expf(x - mi) : 0.f;
            af[jj] = (short)f2bf(p);
        }
        #pragma unroll
        for (int t = 0; t < 4; ++t) {
            s16x8 bf = *(const s16x8*)&lb[(t * 16 + cl) * LBS + koff];
            acc[t] = __builtin_amdgcn_mfma_f32_16x16x32_bf16(af, bf, acc[t], 0, 0, 0);
        }
    }

    float rv[4];
    #pragma unroll
    for (int q = 0; q < 4; ++q) rv[q] = rinv[i0 + lk * 4 + q];
    #pragma unroll
    for (int t = 0; t < 4; ++t) {
        int c = C0 + t * 16 + cl;
        #pragma unroll
        for (int q = 0; q < 4; ++q) {
            int io = i0 + lk * 4 + q;
            float v = acc[t][q] * rv[q];
            v = v > 0.f ? v : expm1f(v);
            out[(size_t)io * DOUT + c] = v;
        }
    }
}

extern "C" void kernel_launch(void* const* d_in, const int* in_sizes, int n_in,
                              void* d_out, int out_size, void* d_ws, size_t ws_size,
                              hipStream_t stream) {
    const float* feat = (const float*)d_in[0];
    const int*   adj  = (const int*)d_in[1];
    const float* W    = (const float*)d_in[2];
    const float* a    = (const float*)d_in[3];
    float* out = (float*)d_out;

    char* ws = (char*)d_ws;
    float*          Wh   = (float*)ws;                            // 8 MB
    unsigned short* WhT  = (unsigned short*)(ws + 8388608);       // 4 MB
    float*          src  = (float*)(ws + 12582912);               // 32 KB
    float*          dst  = (float*)(ws + 12615680);               // 32 KB

    k_wh    <<<512,  256, 0, stream>>>(feat, W, Wh, WhT);
    k_srcdst<<<2048, 256, 0, stream>>>(Wh, a, src, dst);

    if (ws_size >= 180420608ull) {
        // Plan A: materialized normalized bf16 P + pure MFMA GEMM
        unsigned short* P    = (unsigned short*)(ws + 12648448);  // 128 MB
        float*          part = (float*)(ws + 146866176);          // 32 MB (4 x 8 MB)
        k_rowstats_a<<<8192, 256, 0, stream>>>(adj, src, dst, P);
        k_pgemm     <<<256,  512, 0, stream>>>(P, WhT, part);
        k_finish    <<<2048, 256, 0, stream>>>(part, out);
    } else {
        // Fallback: round-1 fused path
        float*        mrow = (float*)(ws + 12648448);
        float*        rinv = (float*)(ws + 12681216);
        unsigned int* bits = (unsigned int*)(ws + 12713984);
        k_rowstats_fb<<<8192, 256, 0, stream>>>(adj, src, dst, mrow, rinv, bits);
        k_attn_fb    <<<512,  256, 0, stream>>>(WhT, src, dst, mrow, rinv, bits, out);
    }
}

// Round 3
// 197.124 us; speedup vs baseline: 1.9760x; 1.2518x over previous
//
#include <hip/hip_runtime.h>
#include <hip/hip_bf16.h>

#define NN   8192
#define DIN  512
#define DOUT 256

typedef __attribute__((ext_vector_type(8))) short s16x8;   // 8 bf16 (A/B frag)
typedef __attribute__((ext_vector_type(4))) float f32x4;   // C/D frag

static __device__ __forceinline__ unsigned short f2bf(float f) {
    union { float f; unsigned u; } v; v.f = f;
    unsigned r = v.u + 0x7fffu + ((v.u >> 16) & 1u);   // RNE
    return (unsigned short)(r >> 16);
}

static __device__ __forceinline__ void gload_lds16(const void* g, void* l) {
    __builtin_amdgcn_global_load_lds(
        (const __attribute__((address_space(1))) unsigned int*)g,
        (__attribute__((address_space(3))) unsigned int*)l, 16, 0, 0);
}

// ---------------- Kernel 1: Wh = feat@W (fp32 regs) -> WhT bf16, src/dst fused -------
__global__ __launch_bounds__(256) void k_wh2(const float* __restrict__ feat,
                                             const float* __restrict__ W,
                                             const float* __restrict__ a,
                                             unsigned short* __restrict__ WhT,
                                             float* __restrict__ src,
                                             float* __restrict__ dst) {
    __shared__ float lf[16 * DIN];                 // 32 KB
    __shared__ float red[2][4][16];
    const int tid = threadIdx.x;
    const int i0  = blockIdx.x * 16;
    const int w   = tid >> 6, lane = tid & 63;

    const float4* fsrc = (const float4*)(feat + (size_t)i0 * DIN);
    float4* fdst = (float4*)lf;
    #pragma unroll
    for (int q = 0; q < 8; ++q) fdst[tid + q * 256] = fsrc[tid + q * 256];
    __syncthreads();

    const int c = tid;
    float outs[16];
    #pragma unroll
    for (int r = 0; r < 16; ++r) outs[r] = 0.f;

    for (int k = 0; k < DIN; k += 4) {
        float w0 = W[(k + 0) * DOUT + c];
        float w1 = W[(k + 1) * DOUT + c];
        float w2 = W[(k + 2) * DOUT + c];
        float w3 = W[(k + 3) * DOUT + c];
        #pragma unroll
        for (int r = 0; r < 16; ++r) {
            float4 f = *(const float4*)&lf[r * DIN + k];   // broadcast read
            outs[r] = fmaf(f.x, w0, fmaf(f.y, w1, fmaf(f.z, w2, fmaf(f.w, w3, outs[r]))));
        }
    }

    unsigned short tb[16];
    #pragma unroll
    for (int r = 0; r < 16; ++r) tb[r] = f2bf(outs[r]);
    uint4* wt = (uint4*)(WhT + (size_t)c * NN + i0);
    wt[0] = *(uint4*)&tb[0];
    wt[1] = *(uint4*)&tb[8];

    // fused src/dst = Wh @ a halves (fp32, exact Wh from registers)
    const float as_ = a[c], ad_ = a[DOUT + c];
    #pragma unroll
    for (int r = 0; r < 16; ++r) {
        float s = outs[r] * as_;
        float d = outs[r] * ad_;
        #pragma unroll
        for (int off = 32; off; off >>= 1) {
            s += __shfl_xor(s, off);
            d += __shfl_xor(d, off);
        }
        if (lane == 0) { red[0][w][r] = s; red[1][w][r] = d; }
    }
    __syncthreads();
    if (tid < 16)
        src[i0 + tid] = red[0][0][tid] + red[0][1][tid] + red[0][2][tid] + red[0][3][tid];
    else if (tid < 32) {
        int r = tid - 16;
        dst[i0 + r] = red[1][0][r] + red[1][1][r] + red[1][2][r] + red[1][3][r];
    }
}

// ---------------- Kernel 2: single-pass masked-exp GEMM with in-register denominator --
// grid = 64 row-tiles x 4 k-split = 256 blocks; block = 512 thr = 8 waves = 4 rg x 2 cg.
// Wave tile 32 rows x 128 cols; BK=64, double-buffered LDS B (WhT slab), adj prefetch.
// No max-subtraction (logits bounded ~12 -> exp <= 2e5, fp32-safe).

#define ATTN_STEP(RD, WR, CUR, NXT, T)                                                   \
{                                                                                        \
    const int k0_ = (T) * 64;                                                            \
    if ((T) < 31) {                                                                      \
        const int kn_ = k0_ + 64;                                                        \
        NXT[0][0][0] = *(const int4*)(adjR0 + kn_);                                      \
        NXT[0][0][1] = *(const int4*)(adjR0 + kn_ + 4);                                  \
        NXT[0][1][0] = *(const int4*)(adjR0 + kn_ + 32);                                 \
        NXT[0][1][1] = *(const int4*)(adjR0 + kn_ + 36);                                 \
        NXT[1][0][0] = *(const int4*)(adjR1 + kn_);                                      \
        NXT[1][0][1] = *(const int4*)(adjR1 + kn_ + 4);                                  \
        NXT[1][1][0] = *(const int4*)(adjR1 + kn_ + 32);                                 \
        NXT[1][1][1] = *(const int4*)(adjR1 + kn_ + 36);                                 \
        const size_t gkb_ = (size_t)(kb0 + kn_) * 2;                                     \
        _Pragma("unroll")                                                                \
        for (int q = 0; q < 4; ++q)                                                      \
            gload_lds16((const char*)WhT + (size_t)rowB[q] * (NN * 2) + gkb_ + kbB[q],   \
                        (char*)(WR) + (q * 512 + tid) * 16);                             \
    }                                                                                    \
    _Pragma("unroll")                                                                    \
    for (int h = 0; h < 2; ++h) {                                                        \
        const int kh_ = k0_ + h * 32 + koff;                                             \
        float4 d0_ = *(const float4*)&ldsD[kh_];                                         \
        float4 d1_ = *(const float4*)&ldsD[kh_ + 4];                                     \
        float dd_[8] = {d0_.x, d0_.y, d0_.z, d0_.w, d1_.x, d1_.y, d1_.z, d1_.w};         \
        s16x8 afm[2];                                                                    \
        _Pragma("unroll")                                                                \
        for (int m = 0; m < 2; ++m) {                                                    \
            int avv[8] = {CUR[m][h][0].x, CUR[m][h][0].y, CUR[m][h][0].z, CUR[m][h][0].w,\
                          CUR[m][h][1].x, CUR[m][h][1].y, CUR[m][h][1].z, CUR[m][h][1].w};\
            float pd_ = 0.f;                                                             \
            _Pragma("unroll")                                                            \
            for (int jj = 0; jj < 8; ++jj) {                                             \
                float x_ = si[m] + dd_[jj];                                              \
                x_ = fmaxf(x_, 0.2f * x_);                                               \
                float p_ = avv[jj] > 0 ? __expf(x_) : 0.f;                               \
                pd_ += p_;                                                               \
                afm[m][jj] = (short)f2bf(p_);                                            \
            }                                                                            \
            den[m] += pd_;                                                               \
        }                                                                                \
        const int kwh_ = h * 64 + lk * 16;                                               \
        _Pragma("unroll")                                                                \
        for (int n = 0; n < 8; ++n) {                                                    \
            const int col_ = c0 + n * 16 + cl;                                           \
            s16x8 bfv = *(const s16x8*)((const char*)(RD) + col_ * 128 +                 \
                                        (kwh_ ^ ((col_ & 7) << 4)));                     \
            acc[0][n] = __builtin_amdgcn_mfma_f32_16x16x32_bf16(afm[0], bfv, acc[0][n], 0, 0, 0); \
            acc[1][n] = __builtin_amdgcn_mfma_f32_16x16x32_bf16(afm[1], bfv, acc[1][n], 0, 0, 0); \
        }                                                                                \
    }                                                                                    \
    __syncthreads();                                                                     \
}

__global__ __launch_bounds__(512, 2) void k_attn2(const int* __restrict__ adj,
                                                  const unsigned short* __restrict__ WhT,
                                                  const float* __restrict__ src,
                                                  const float* __restrict__ dstg,
                                                  float* __restrict__ denp,
                                                  float* __restrict__ part) {
    __shared__ __attribute__((aligned(16))) char Bs[2][32768];   // 64 KB dbuf WhT slab
    __shared__ float4 ldsD4[512];                                // dst k-chunk (8 KB)
    const float* ldsD = (const float*)ldsD4;

    const int tid = threadIdx.x;
    const int w   = tid >> 6, lane = tid & 63;
    const int cl  = lane & 15, lk = lane >> 4;
    const int koff = lk * 8;
    const int rg  = w >> 1, cg = w & 1;
    const int c0  = cg * 128;
    const int rt  = blockIdx.x & 63;
    const int ks  = blockIdx.x >> 6;
    const int kb0 = ks * 2048;
    const int rowbase = rt * 128 + rg * 32;
    const int ia0 = rowbase + cl;
    const int ia1 = rowbase + 16 + cl;

    const int* adjR0 = adj + (size_t)ia0 * NN + kb0 + koff;
    const int* adjR1 = adj + (size_t)ia1 * NN + kb0 + koff;

    float si[2];
    si[0] = src[ia0];
    si[1] = src[ia1];

    // staging maps (pre-swizzled global source, linear LDS dest)
    int rowB[4], kbB[4];
    #pragma unroll
    for (int q = 0; q < 4; ++q) {
        int chunk = q * 512 + tid;
        rowB[q] = chunk >> 3;
        kbB[q]  = ((chunk & 7) * 16) ^ ((rowB[q] & 7) << 4);
    }

    f32x4 acc[2][8];
    #pragma unroll
    for (int m = 0; m < 2; ++m)
        #pragma unroll
        for (int n = 0; n < 8; ++n) { acc[m][n][0]=0.f; acc[m][n][1]=0.f; acc[m][n][2]=0.f; acc[m][n][3]=0.f; }
    float den[2] = {0.f, 0.f};

    // prologue: dst chunk -> LDS, B(t=0) -> Bs[0], adj(t=0) -> Ca
    ldsD4[tid] = *(const float4*)(dstg + kb0 + tid * 4);
    #pragma unroll
    for (int q = 0; q < 4; ++q)
        gload_lds16((const char*)WhT + (size_t)rowB[q] * (NN * 2) + (size_t)kb0 * 2 + kbB[q],
                    (char*)Bs[0] + (q * 512 + tid) * 16);
    int4 Ca[2][2][2], Cb[2][2][2];
    Ca[0][0][0] = *(const int4*)(adjR0);      Ca[0][0][1] = *(const int4*)(adjR0 + 4);
    Ca[0][1][0] = *(const int4*)(adjR0 + 32); Ca[0][1][1] = *(const int4*)(adjR0 + 36);
    Ca[1][0][0] = *(const int4*)(adjR1);      Ca[1][0][1] = *(const int4*)(adjR1 + 4);
    Ca[1][1][0] = *(const int4*)(adjR1 + 32); Ca[1][1][1] = *(const int4*)(adjR1 + 36);
    __syncthreads();

    char* bufA = (char*)Bs[0];
    char* bufB = (char*)Bs[1];
    for (int it = 0; it < 16; ++it) {
        ATTN_STEP(bufA, bufB, Ca, Cb, 2 * it);
        ATTN_STEP(bufB, bufA, Cb, Ca, 2 * it + 1);
    }

    // denominator: reduce over the 4 lk groups (each covered a disjoint k-slice)
    den[0] += __shfl_xor(den[0], 16); den[0] += __shfl_xor(den[0], 32);
    den[1] += __shfl_xor(den[1], 16); den[1] += __shfl_xor(den[1], 32);
    if (cg == 0 && lk == 0) {
        denp[(size_t)ks * NN + ia0] = den[0];
        denp[(size_t)ks * NN + ia1] = den[1];
    }

    float* pp = part + (size_t)ks * (NN * DOUT);
    #pragma unroll
    for (int m = 0; m < 2; ++m) {
        #pragma unroll
        for (int n = 0; n < 8; ++n) {
            const int colg = c0 + n * 16 + cl;
            #pragma unroll
            for (int q = 0; q < 4; ++q) {
                const int rowg = rowbase + m * 16 + lk * 4 + q;
                pp[(size_t)rowg * DOUT + colg] = acc[m][n][q];
            }
        }
    }
}

// ---------------- Kernel 3: out = elu( (sum_ks num) / (sum_ks den) ) -----------------
__global__ __launch_bounds__(256) void k_finish2(const float* __restrict__ part,
                                                 const float* __restrict__ denp,
                                                 float* __restrict__ out) {
    const int idx = blockIdx.x * 256 + threadIdx.x;   // float4 units
    const int row = idx >> 6;                          // 64 float4 per row
    float den = denp[row] + denp[NN + row] + denp[2 * NN + row] + denp[3 * NN + row];
    float rv = den > 0.f ? 1.f / den : 0.f;
    const int st = NN * DOUT / 4;
    const float4* p = (const float4*)part;
    float4 va = p[idx], vb = p[idx + st], vc = p[idx + 2 * st], vd = p[idx + 3 * st];
    float4 s;
    s.x = (va.x + vb.x + vc.x + vd.x) * rv;
    s.y = (va.y + vb.y + vc.y + vd.y) * rv;
    s.z = (va.z + vb.z + vc.z + vd.z) * rv;
    s.w = (va.w + vb.w + vc.w + vd.w) * rv;
    s.x = s.x > 0.f ? s.x : expm1f(s.x);
    s.y = s.y > 0.f ? s.y : expm1f(s.y);
    s.z = s.z > 0.f ? s.z : expm1f(s.z);
    s.w = s.w > 0.f ? s.w : expm1f(s.w);
    ((float4*)out)[idx] = s;
}

extern "C" void kernel_launch(void* const* d_in, const int* in_sizes, int n_in,
                              void* d_out, int out_size, void* d_ws, size_t ws_size,
                              hipStream_t stream) {
    const float* feat = (const float*)d_in[0];
    const int*   adj  = (const int*)d_in[1];
    const float* W    = (const float*)d_in[2];
    const float* a    = (const float*)d_in[3];
    float* out = (float*)d_out;

    char* ws = (char*)d_ws;
    unsigned short* WhT  = (unsigned short*)ws;               // 4 MB
    float*          src  = (float*)(ws + 4194304);            // 32 KB
    float*          dst  = (float*)(ws + 4227072);            // 32 KB
    float*          denp = (float*)(ws + 4259840);            // 128 KB
    float*          part = (float*)(ws + 4390912);            // 32 MB (4 x 8 MB)

    k_wh2    <<<512,  256, 0, stream>>>(feat, W, a, WhT, src, dst);
    k_attn2  <<<256,  512, 0, stream>>>(adj, WhT, src, dst, denp, part);
    k_finish2<<<2048, 256, 0, stream>>>(part, denp, out);
}

// Round 4
// 185.851 us; speedup vs baseline: 2.0959x; 1.0607x over previous
//
#include <hip/hip_runtime.h>
#include <hip/hip_bf16.h>

#define NN   8192
#define DIN  512
#define DOUT 256

typedef __attribute__((ext_vector_type(8)))  short s16x8;   // 8 bf16 (A/B frag)
typedef __attribute__((ext_vector_type(16))) float f32x16;  // 32x32 C/D frag

static __device__ __forceinline__ unsigned short f2bf(float f) {
    union { float f; unsigned u; } v; v.f = f;
    unsigned r = v.u + 0x7fffu + ((v.u >> 16) & 1u);   // RNE
    return (unsigned short)(r >> 16);
}

static __device__ __forceinline__ void gload_lds16(const void* g, void* l) {
    __builtin_amdgcn_global_load_lds(
        (const __attribute__((address_space(1))) unsigned int*)g,
        (__attribute__((address_space(3))) unsigned int*)l, 16, 0, 0);
}

// ---------------- Kernel 1: Wh = feat@W (fp32 regs) -> WhT bf16, src/dst fused -------
__global__ __launch_bounds__(256) void k_wh2(const float* __restrict__ feat,
                                             const float* __restrict__ W,
                                             const float* __restrict__ a,
                                             unsigned short* __restrict__ WhT,
                                             float* __restrict__ src,
                                             float* __restrict__ dst) {
    __shared__ float lf[16 * DIN];                 // 32 KB
    __shared__ float red[2][4][16];
    const int tid = threadIdx.x;
    const int i0  = blockIdx.x * 16;
    const int w   = tid >> 6, lane = tid & 63;

    const float4* fsrc = (const float4*)(feat + (size_t)i0 * DIN);
    float4* fdst = (float4*)lf;
    #pragma unroll
    for (int q = 0; q < 8; ++q) fdst[tid + q * 256] = fsrc[tid + q * 256];
    __syncthreads();

    const int c = tid;
    float outs[16];
    #pragma unroll
    for (int r = 0; r < 16; ++r) outs[r] = 0.f;

    for (int k = 0; k < DIN; k += 4) {
        float w0 = W[(k + 0) * DOUT + c];
        float w1 = W[(k + 1) * DOUT + c];
        float w2 = W[(k + 2) * DOUT + c];
        float w3 = W[(k + 3) * DOUT + c];
        #pragma unroll
        for (int r = 0; r < 16; ++r) {
            float4 f = *(const float4*)&lf[r * DIN + k];   // broadcast read
            outs[r] = fmaf(f.x, w0, fmaf(f.y, w1, fmaf(f.z, w2, fmaf(f.w, w3, outs[r]))));
        }
    }

    unsigned short tb[16];
    #pragma unroll
    for (int r = 0; r < 16; ++r) tb[r] = f2bf(outs[r]);
    uint4* wt = (uint4*)(WhT + (size_t)c * NN + i0);
    wt[0] = *(uint4*)&tb[0];
    wt[1] = *(uint4*)&tb[8];

    // fused src/dst = Wh @ a halves (fp32, exact Wh from registers)
    const float as_ = a[c], ad_ = a[DOUT + c];
    #pragma unroll
    for (int r = 0; r < 16; ++r) {
        float s = outs[r] * as_;
        float d = outs[r] * ad_;
        #pragma unroll
        for (int off = 32; off; off >>= 1) {
            s += __shfl_xor(s, off);
            d += __shfl_xor(d, off);
        }
        if (lane == 0) { red[0][w][r] = s; red[1][w][r] = d; }
    }
    __syncthreads();
    if (tid < 16)
        src[i0 + tid] = red[0][0][tid] + red[0][1][tid] + red[0][2][tid] + red[0][3][tid];
    else if (tid < 32) {
        int r = tid - 16;
        dst[i0 + r] = red[1][0][r] + red[1][1][r] + red[1][2][r] + red[1][3][r];
    }
}

// ---------------- Kernel 2: single-pass masked-exp GEMM, P-in-LDS, 32x32x16 MFMA -----
// grid = 128 row-tiles x 4 ksplit = 512 blocks (2/CU). block = 512 thr = 8 waves.
// BM=64 rows, C=256 cols; wave tile 64 rows x 32 cols (2 m x 4 ksub = 8 MFMA/step).
// Each P value built EXACTLY ONCE (thread r=tid>>3, kb=tid&7 covers P[r][kb*8..+8]).
// LDS: Bs dbuf 2x32KB + P slab 8KB = 72 KB -> 2 blocks/CU.
__global__ __launch_bounds__(512, 4) void k_attn3(const int* __restrict__ adj,
                                                  const unsigned short* __restrict__ WhT,
                                                  const float* __restrict__ src,
                                                  const float* __restrict__ dstg,
                                                  float* __restrict__ denp,
                                                  float* __restrict__ part) {
    __shared__ __attribute__((aligned(16))) char Bs[2][32768];  // WhT slab [256 col][64 k] swz
    __shared__ __attribute__((aligned(16))) char Pl[8192];      // P slab [64 row][64 k] swz

    const int tid  = threadIdx.x;
    const int lane = tid & 63;
    const int w    = tid >> 6;
    const int l31  = lane & 31, lhi = lane >> 5;
    const int c0w  = w * 32;

    const int rt  = blockIdx.x & 127;
    const int ks  = blockIdx.x >> 7;           // 0..3
    const int kb0 = ks * 2048;

    // builder role: row r, k-block kb (8 consecutive k)
    const int r  = tid >> 3, kb = tid & 7;
    const int gr = rt * 64 + r;
    const float si = src[gr];
    const int*   adjR = adj  + (size_t)gr * NN + kb0 + kb * 8;
    const float* dstp = dstg +                   kb0 + kb * 8;
    const int pbyte = r * 128 + ((kb * 16) ^ ((r & 7) << 4));

    // B staging maps (pre-swizzled global source, linear LDS dest)
    int colB[4], kbB[4];
    #pragma unroll
    for (int q = 0; q < 4; ++q) {
        int chunk = q * 512 + tid;
        colB[q] = chunk >> 3;
        kbB[q]  = ((chunk & 7) * 16) ^ ((colB[q] & 7) << 4);
    }

    f32x16 acc[2];
    #pragma unroll
    for (int mt = 0; mt < 2; ++mt)
        #pragma unroll
        for (int e = 0; e < 16; ++e) acc[mt][e] = 0.f;
    float den = 0.f;

    // prologue: stage B[t=0] -> Bs[0]; adj[t=0] -> regs
    #pragma unroll
    for (int q = 0; q < 4; ++q)
        gload_lds16((const char*)WhT + (size_t)colB[q] * (NN * 2) + (size_t)kb0 * 2 + kbB[q],
                    (char*)Bs[0] + (q * 512 + tid) * 16);
    int4 a0 = *(const int4*)(adjR);
    int4 a1 = *(const int4*)(adjR + 4);
    __syncthreads();

    for (int t = 0; t < 32; ++t) {
        const int cur = t & 1;
        // ---- phase 1: prefetch t+1 (adj regs + B slab), build P(t) ----
        int4 na0, na1;
        if (t < 31) {
            na0 = *(const int4*)(adjR + (t + 1) * 64);
            na1 = *(const int4*)(adjR + (t + 1) * 64 + 4);
            const size_t gkb = (size_t)(kb0 + (t + 1) * 64) * 2;
            #pragma unroll
            for (int q = 0; q < 4; ++q)
                gload_lds16((const char*)WhT + (size_t)colB[q] * (NN * 2) + gkb + kbB[q],
                            (char*)Bs[cur ^ 1] + (q * 512 + tid) * 16);
        }
        float4 d0 = *(const float4*)(dstp + t * 64);
        float4 d1 = *(const float4*)(dstp + t * 64 + 4);
        const float dd[8] = {d0.x, d0.y, d0.z, d0.w, d1.x, d1.y, d1.z, d1.w};
        const int   va[8] = {a0.x, a0.y, a0.z, a0.w, a1.x, a1.y, a1.z, a1.w};
        s16x8 pw;
        #pragma unroll
        for (int jj = 0; jj < 8; ++jj) {
            float x = si + dd[jj];
            x = fmaxf(x, 0.2f * x);                 // leaky_relu 0.2
            float p = va[jj] > 0 ? __expf(x) : 0.f; // no max-sub: logits bounded (~12)
            den += p;
            pw[jj] = (short)f2bf(p);
        }
        *(s16x8*)(Pl + pbyte) = pw;
        a0 = na0; a1 = na1;
        __syncthreads();   // P visible; B[t] resident (staged last iter, drained then)

        // ---- phase 2: 8x MFMA 32x32x16 from Pl + Bs[cur] ----
        #pragma unroll
        for (int ks4 = 0; ks4 < 4; ++ks4) {
            const int kbyte = ks4 * 32 + lhi * 16;
            const int colg  = c0w + l31;
            s16x8 bf = *(const s16x8*)(Bs[cur] + colg * 128 + (kbyte ^ ((colg & 7) << 4)));
            #pragma unroll
            for (int mt = 0; mt < 2; ++mt) {
                const int row = mt * 32 + l31;
                s16x8 af = *(const s16x8*)(Pl + row * 128 + (kbyte ^ ((row & 7) << 4)));
                acc[mt] = __builtin_amdgcn_mfma_f32_32x32x16_bf16(af, bf, acc[mt], 0, 0, 0);
            }
        }
        __syncthreads();   // P consumed -> safe to overwrite next iter
    }

    // denominator: reduce over the 8 kb lanes (lane bits 0..2)
    den += __shfl_xor(den, 1);
    den += __shfl_xor(den, 2);
    den += __shfl_xor(den, 4);
    if ((tid & 7) == 0) denp[(size_t)ks * NN + gr] = den;

    // epilogue: C/D layout (m74/m101): col = lane&31, row = (reg&3)+8*(reg>>2)+4*lhi
    float* pp = part + (size_t)ks * (NN * DOUT);
    #pragma unroll
    for (int mt = 0; mt < 2; ++mt) {
        #pragma unroll
        for (int e = 0; e < 16; ++e) {
            const int row = rt * 64 + mt * 32 + (e & 3) + 8 * (e >> 2) + 4 * lhi;
            pp[(size_t)row * DOUT + c0w + l31] = acc[mt][e];
        }
    }
}

// ---------------- Kernel 3: out = elu( (sum_ks num) / (sum_ks den) ) -----------------
__global__ __launch_bounds__(256) void k_finish2(const float* __restrict__ part,
                                                 const float* __restrict__ denp,
                                                 float* __restrict__ out) {
    const int idx = blockIdx.x * 256 + threadIdx.x;   // float4 units
    const int row = idx >> 6;                          // 64 float4 per row
    float den = denp[row] + denp[NN + row] + denp[2 * NN + row] + denp[3 * NN + row];
    float rv = den > 0.f ? 1.f / den : 0.f;
    const int st = NN * DOUT / 4;
    const float4* p = (const float4*)part;
    float4 va = p[idx], vb = p[idx + st], vc = p[idx + 2 * st], vd = p[idx + 3 * st];
    float4 s;
    s.x = (va.x + vb.x + vc.x + vd.x) * rv;
    s.y = (va.y + vb.y + vc.y + vd.y) * rv;
    s.z = (va.z + vb.z + vc.z + vd.z) * rv;
    s.w = (va.w + vb.w + vc.w + vd.w) * rv;
    s.x = s.x > 0.f ? s.x : expm1f(s.x);
    s.y = s.y > 0.f ? s.y : expm1f(s.y);
    s.z = s.z > 0.f ? s.z : expm1f(s.z);
    s.w = s.w > 0.f ? s.w : expm1f(s.w);
    ((float4*)out)[idx] = s;
}

extern "C" void kernel_launch(void* const* d_in, const int* in_sizes, int n_in,
                              void* d_out, int out_size, void* d_ws, size_t ws_size,
                              hipStream_t stream) {
    const float* feat = (const float*)d_in[0];
    const int*   adj  = (const int*)d_in[1];
    const float* W    = (const float*)d_in[2];
    const float* a    = (const float*)d_in[3];
    float* out = (float*)d_out;

    char* ws = (char*)d_ws;
    unsigned short* WhT  = (unsigned short*)ws;               // 4 MB
    float*          src  = (float*)(ws + 4194304);            // 32 KB
    float*          dst  = (float*)(ws + 4227072);            // 32 KB
    float*          denp = (float*)(ws + 4259840);            // 128 KB
    float*          part = (float*)(ws + 4390912);            // 32 MB (4 x 8 MB)

    k_wh2    <<<512,  256, 0, stream>>>(feat, W, a, WhT, src, dst);
    k_attn3  <<<512,  512, 0, stream>>>(adj, WhT, src, dst, denp, part);
    k_finish2<<<2048, 256, 0, stream>>>(part, denp, out);
}

// Round 5
// 180.255 us; speedup vs baseline: 2.1609x; 1.0310x over previous
//
#include <hip/hip_runtime.h>
#include <hip/hip_bf16.h>

#define NN   8192
#define DIN  512
#define DOUT 256

typedef __attribute__((ext_vector_type(8)))  short s16x8;   // 8 bf16 (A/B frag)
typedef __attribute__((ext_vector_type(16))) float f32x16;  // 32x32 C/D frag

static __device__ __forceinline__ unsigned short f2bf(float f) {
    union { float f; unsigned u; } v; v.f = f;
    unsigned r = v.u + 0x7fffu + ((v.u >> 16) & 1u);   // RNE
    return (unsigned short)(r >> 16);
}

static __device__ __forceinline__ void gload_lds16(const void* g, void* l) {
    __builtin_amdgcn_global_load_lds(
        (const __attribute__((address_space(1))) unsigned int*)g,
        (__attribute__((address_space(3))) unsigned int*)l, 16, 0, 0);
}

// ---------------- Kernel 1: Wh = feat@W (fp32 regs) -> WhT bf16, src/dst fused -------
__global__ __launch_bounds__(256) void k_wh2(const float* __restrict__ feat,
                                             const float* __restrict__ W,
                                             const float* __restrict__ a,
                                             unsigned short* __restrict__ WhT,
                                             float* __restrict__ src,
                                             float* __restrict__ dst) {
    __shared__ float lf[16 * DIN];                 // 32 KB
    __shared__ float red[2][4][16];
    const int tid = threadIdx.x;
    const int i0  = blockIdx.x * 16;
    const int w   = tid >> 6, lane = tid & 63;

    const float4* fsrc = (const float4*)(feat + (size_t)i0 * DIN);
    float4* fdst = (float4*)lf;
    #pragma unroll
    for (int q = 0; q < 8; ++q) fdst[tid + q * 256] = fsrc[tid + q * 256];
    __syncthreads();

    const int c = tid;
    float outs[16];
    #pragma unroll
    for (int r = 0; r < 16; ++r) outs[r] = 0.f;

    for (int k = 0; k < DIN; k += 4) {
        float w0 = W[(k + 0) * DOUT + c];
        float w1 = W[(k + 1) * DOUT + c];
        float w2 = W[(k + 2) * DOUT + c];
        float w3 = W[(k + 3) * DOUT + c];
        #pragma unroll
        for (int r = 0; r < 16; ++r) {
            float4 f = *(const float4*)&lf[r * DIN + k];   // broadcast read
            outs[r] = fmaf(f.x, w0, fmaf(f.y, w1, fmaf(f.z, w2, fmaf(f.w, w3, outs[r]))));
        }
    }

    unsigned short tb[16];
    #pragma unroll
    for (int r = 0; r < 16; ++r) tb[r] = f2bf(outs[r]);
    uint4* wt = (uint4*)(WhT + (size_t)c * NN + i0);
    wt[0] = *(uint4*)&tb[0];
    wt[1] = *(uint4*)&tb[8];

    // fused src/dst = Wh @ a halves (fp32, exact Wh from registers)
    const float as_ = a[c], ad_ = a[DOUT + c];
    #pragma unroll
    for (int r = 0; r < 16; ++r) {
        float s = outs[r] * as_;
        float d = outs[r] * ad_;
        #pragma unroll
        for (int off = 32; off; off >>= 1) {
            s += __shfl_xor(s, off);
            d += __shfl_xor(d, off);
        }
        if (lane == 0) { red[0][w][r] = s; red[1][w][r] = d; }
    }
    __syncthreads();
    if (tid < 16)
        src[i0 + tid] = red[0][0][tid] + red[0][1][tid] + red[0][2][tid] + red[0][3][tid];
    else if (tid < 32) {
        int r = tid - 16;
        dst[i0 + r] = red[1][0][r] + red[1][1][r] + red[1][2][r] + red[1][3][r];
    }
}

// ---------------- Kernel 2: single-pass masked-exp GEMM, T4 counted-vmcnt pipeline ---
// grid = 128 row-tiles x 4 ksplit = 512 blocks (2/CU, 80 KB LDS). block = 512 = 8 waves.
// BM=64 rows x 256 cols; wave tile 64x32 via 32x32x16 MFMA (2m x 4ksub = 8 MFMA/step).
// ONE raw s_barrier per step; s_waitcnt vmcnt(2) keeps adj(t+1) in flight across it.
// Race-safety: B(t+1) staged into Bs[cur^1] only AFTER barrier(t) (all waves done
// reading Bs[cur^1] at MFMA(t-1)); Pl double-buffered for the same reason.

#define STEP_BODY(T, CUR, A0, A1, NA0, NA1)                                              \
{                                                                                        \
    /* pre-barrier: issue adj(T+1) (depth-2), build P(T) -> Pl[CUR] */                   \
    {                                                                                    \
        const int tn_ = ((T) < 31) ? (T) + 1 : 31;   /* clamp keeps vmcnt uniform */     \
        NA0 = *(const int4*)(adjR + tn_ * 64);                                           \
        NA1 = *(const int4*)(adjR + tn_ * 64 + 4);                                       \
    }                                                                                    \
    {                                                                                    \
        float4 d0_ = *(const float4*)(dstp + (T) * 64);                                  \
        float4 d1_ = *(const float4*)(dstp + (T) * 64 + 4);                              \
        const float dd_[8] = {d0_.x, d0_.y, d0_.z, d0_.w, d1_.x, d1_.y, d1_.z, d1_.w};   \
        const int   va_[8] = {A0.x, A0.y, A0.z, A0.w, A1.x, A1.y, A1.z, A1.w};           \
        s16x8 pw_;                                                                       \
        _Pragma("unroll")                                                                \
        for (int jj = 0; jj < 8; ++jj) {                                                 \
            float x_ = si + dd_[jj];                                                     \
            x_ = fmaxf(x_, 0.2f * x_);                  /* leaky_relu 0.2 */             \
            float p_ = va_[jj] > 0 ? __expf(x_) : 0.f;  /* logits bounded -> no maxsub */\
            den += p_;                                                                   \
            pw_[jj] = (short)f2bf(p_);                                                   \
        }                                                                                \
        *(s16x8*)(Pl[CUR] + pbyte) = pw_;                                                \
    }                                                                                    \
    __builtin_amdgcn_sched_barrier(0);                                                   \
    asm volatile("s_waitcnt vmcnt(2) lgkmcnt(0)" ::: "memory");                          \
    __builtin_amdgcn_s_barrier();                                                        \
    __builtin_amdgcn_sched_barrier(0);                                                   \
    /* post-barrier: stage B(T+1) -> Bs[CUR^1]; MFMA(T) from Pl[CUR] + Bs[CUR] */        \
    {                                                                                    \
        const int tn_ = ((T) < 31) ? (T) + 1 : 31;                                       \
        const size_t gkb_ = (size_t)(kb0 + tn_ * 64) * 2;                                \
        _Pragma("unroll")                                                                \
        for (int q = 0; q < 4; ++q)                                                      \
            gload_lds16((const char*)WhT + (size_t)colB[q] * (NN * 2) + gkb_ + kbB[q],   \
                        Bs[(CUR) ^ 1] + (q * 512 + tid) * 16);                           \
    }                                                                                    \
    _Pragma("unroll")                                                                    \
    for (int ks4 = 0; ks4 < 4; ++ks4) {                                                  \
        const int kbyte_ = ks4 * 32 + lhi * 16;                                          \
        const int colg_  = c0w + l31;                                                    \
        s16x8 bfv_ = *(const s16x8*)(Bs[CUR] + colg_ * 128 +                             \
                                     (kbyte_ ^ ((colg_ & 7) << 4)));                     \
        _Pragma("unroll")                                                                \
        for (int mt = 0; mt < 2; ++mt) {                                                 \
            const int row_ = mt * 32 + l31;                                              \
            s16x8 afv_ = *(const s16x8*)(Pl[CUR] + row_ * 128 +                          \
                                         (kbyte_ ^ ((row_ & 7) << 4)));                  \
            acc[mt] = __builtin_amdgcn_mfma_f32_32x32x16_bf16(afv_, bfv_, acc[mt], 0, 0, 0); \
        }                                                                                \
    }                                                                                    \
}

__global__ __launch_bounds__(512, 4) void k_attn4(const int* __restrict__ adj,
                                                  const unsigned short* __restrict__ WhT,
                                                  const float* __restrict__ src,
                                                  const float* __restrict__ dstg,
                                                  float* __restrict__ denp,
                                                  float* __restrict__ part) {
    __shared__ __attribute__((aligned(16))) char Bs[2][32768];  // WhT slab [256 col][64 k] swz
    __shared__ __attribute__((aligned(16))) char Pl[2][8192];   // P slab  [64 row][64 k] swz

    const int tid  = threadIdx.x;
    const int lane = tid & 63;
    const int w    = tid >> 6;
    const int l31  = lane & 31, lhi = lane >> 5;
    const int c0w  = w * 32;

    const int rt  = blockIdx.x & 127;
    const int ks  = blockIdx.x >> 7;           // 0..3
    const int kb0 = ks * 2048;

    // builder role: row r, k-block kb (8 consecutive k)
    const int r  = tid >> 3, kb = tid & 7;
    const int gr = rt * 64 + r;
    const float si = src[gr];
    const int*   adjR = adj  + (size_t)gr * NN + kb0 + kb * 8;
    const float* dstp = dstg +                   kb0 + kb * 8;
    const int pbyte = r * 128 + ((kb * 16) ^ ((r & 7) << 4));

    // B staging maps (pre-swizzled global source, linear LDS dest)
    int colB[4], kbB[4];
    #pragma unroll
    for (int q = 0; q < 4; ++q) {
        int chunk = q * 512 + tid;
        colB[q] = chunk >> 3;
        kbB[q]  = ((chunk & 7) * 16) ^ ((colB[q] & 7) << 4);
    }

    f32x16 acc[2];
    #pragma unroll
    for (int mt = 0; mt < 2; ++mt)
        #pragma unroll
        for (int e = 0; e < 16; ++e) acc[mt][e] = 0.f;
    float den = 0.f;

    // prologue: stage B(0) -> Bs[0] FIRST, then adj(0) (in-order retire: waiting
    // adj(0) at the first build implies B(0) landed).
    #pragma unroll
    for (int q = 0; q < 4; ++q)
        gload_lds16((const char*)WhT + (size_t)colB[q] * (NN * 2) + (size_t)kb0 * 2 + kbB[q],
                    Bs[0] + (q * 512 + tid) * 16);
    int4 a0 = *(const int4*)(adjR);
    int4 a1 = *(const int4*)(adjR + 4);
    int4 n0, n1;

    for (int tt = 0; tt < 16; ++tt) {
        STEP_BODY(2 * tt,     0, a0, a1, n0, n1);
        STEP_BODY(2 * tt + 1, 1, n0, n1, a0, a1);
    }

    // denominator: reduce over the 8 kb lanes (lane bits 0..2)
    den += __shfl_xor(den, 1);
    den += __shfl_xor(den, 2);
    den += __shfl_xor(den, 4);
    if ((tid & 7) == 0) denp[(size_t)ks * NN + gr] = den;

    // epilogue: C/D layout (m74/m101): col = lane&31, row = (reg&3)+8*(reg>>2)+4*lhi
    float* pp = part + (size_t)ks * (NN * DOUT);
    #pragma unroll
    for (int mt = 0; mt < 2; ++mt) {
        #pragma unroll
        for (int e = 0; e < 16; ++e) {
            const int row = rt * 64 + mt * 32 + (e & 3) + 8 * (e >> 2) + 4 * lhi;
            pp[(size_t)row * DOUT + c0w + l31] = acc[mt][e];
        }
    }
}

// ---------------- Kernel 3: out = elu( (sum_ks num) / (sum_ks den) ) -----------------
__global__ __launch_bounds__(256) void k_finish2(const float* __restrict__ part,
                                                 const float* __restrict__ denp,
                                                 float* __restrict__ out) {
    const int idx = blockIdx.x * 256 + threadIdx.x;   // float4 units
    const int row = idx >> 6;                          // 64 float4 per row
    float den = denp[row] + denp[NN + row] + denp[2 * NN + row] + denp[3 * NN + row];
    float rv = den > 0.f ? 1.f / den : 0.f;
    const int st = NN * DOUT / 4;
    const float4* p = (const float4*)part;
    float4 va = p[idx], vb = p[idx + st], vc = p[idx + 2 * st], vd = p[idx + 3 * st];
    float4 s;
    s.x = (va.x + vb.x + vc.x + vd.x) * rv;
    s.y = (va.y + vb.y + vc.y + vd.y) * rv;
    s.z = (va.z + vb.z + vc.z + vd.z) * rv;
    s.w = (va.w + vb.w + vc.w + vd.w) * rv;
    s.x = s.x > 0.f ? s.x : expm1f(s.x);
    s.y = s.y > 0.f ? s.y : expm1f(s.y);
    s.z = s.z > 0.f ? s.z : expm1f(s.z);
    s.w = s.w > 0.f ? s.w : expm1f(s.w);
    ((float4*)out)[idx] = s;
}

extern "C" void kernel_launch(void* const* d_in, const int* in_sizes, int n_in,
                              void* d_out, int out_size, void* d_ws, size_t ws_size,
                              hipStream_t stream) {
    const float* feat = (const float*)d_in[0];
    const int*   adj  = (const int*)d_in[1];
    const float* W    = (const float*)d_in[2];
    const float* a    = (const float*)d_in[3];
    float* out = (float*)d_out;

    char* ws = (char*)d_ws;
    unsigned short* WhT  = (unsigned short*)ws;               // 4 MB
    float*          src  = (float*)(ws + 4194304);            // 32 KB
    float*          dst  = (float*)(ws + 4227072);            // 32 KB
    float*          denp = (float*)(ws + 4259840);            // 128 KB
    float*          part = (float*)(ws + 4390912);            // 32 MB (4 x 8 MB)

    k_wh2    <<<512,  256, 0, stream>>>(feat, W, a, WhT, src, dst);
    k_attn4  <<<512,  512, 0, stream>>>(adj, WhT, src, dst, denp, part);
    k_finish2<<<2048, 256, 0, stream>>>(part, denp, out);
}